// Round 21
// baseline (19770.238 us; speedup 1.0000x reference)
//
#include <hip/hip_runtime.h>
#include <math.h>

#define BS 128
#define L 512
#define ENC 512
#define DEC 1024
#define ATTN 512
#define EMB 256
#define VOCAB 128
#define TMAX 128
#define KCAT 1792  // EMB+ENC+DEC
#define G4 4096    // 4*DEC

// ---- workspace layout (float offsets) ----
#define OFF_WET    0ull                       // [BS][L][ATTN]     33554432
#define OFF_WGR    33554432ull                // [G4][KCAT] d-major 7340032
#define OFF_BGR    40894464ull                // [G4] d-major          4096
#define OFF_WOUTT  40898560ull                // [DEC][VOCAB]        131072
#define OFF_WDT    41029632ull                // [DEC][ATTN]         524288
#define OFF_C0     41553920ull                // [BS][DEC]           131072
#define OFF_C1     41684992ull                // [BS][DEC]           131072
#define OFF_SCP    41816064ull                // [2][BS][L] partials 131072
#define OFF_LP2    41947136ull                // [2][BS][VOCAB] logit partials 32768
#define OFF_XCAT   41979904ull                // [BS][KCAT]          229376
#define OFF_GPART  42209280ull                // [4][BS][G4]        2097152
#define OFF_FLAG   44306432ull                // [BS*16] pair flags    2048
// end: 44308480 floats = 177.2 MB

// branch-free tanh: exp + Newton-refined rcp, ~3e-7 rel err
__device__ __forceinline__ float tanh_fast(float x) {
    float ax = fabsf(x);
    float e = __expf(-2.f * ax);
    float d = 1.f + e;
    float r = __builtin_amdgcn_rcpf(d);
    r = r * (2.f - d * r);
    float t = 1.f - 2.f * e * r;
    return copysignf(t, x);
}

// 2-block pair barrier: monotonic counter, relaxed spin (2 pollers/line)
__device__ __forceinline__ void pairsync(int* flag, int target) {
    __syncthreads();
    if (threadIdx.x == 0) {
        __threadfence();  // release prior global writes
        __hip_atomic_fetch_add(flag, 1, __ATOMIC_ACQ_REL, __HIP_MEMORY_SCOPE_AGENT);
        while (__hip_atomic_load(flag, __ATOMIC_RELAXED, __HIP_MEMORY_SCOPE_AGENT) < target) {
            __builtin_amdgcn_s_sleep(4);
        }
        __threadfence();  // acquire partner's writes
    }
    __syncthreads();
}

// ---------------- one-time prep: d-major W_gate concat, bias sum, W_out^T, W_dec^T ----------------
__global__ void k_prep(const float* __restrict__ W_ih, const float* __restrict__ W_hh,
                       const float* __restrict__ b_ih, const float* __restrict__ b_hh,
                       const float* __restrict__ W_out, const float* __restrict__ W_dec,
                       float* __restrict__ Wgr, float* __restrict__ bgr,
                       float* __restrict__ WoutT, float* __restrict__ WdT) {
    long i = (long)blockIdx.x * 256 + threadIdx.x;
    if (i < (long)G4 * KCAT) {
        int mp = (int)(i / KCAT), k = (int)(i % KCAT);
        int d = mp >> 2, g = mp & 3;
        int r = g * DEC + d;
        Wgr[i] = (k < EMB + ENC) ? W_ih[(long)r * (EMB + ENC) + k]
                                 : W_hh[(long)r * DEC + (k - (EMB + ENC))];
        return;
    }
    long j = i - (long)G4 * KCAT;
    if (j < G4) {
        int d = (int)(j >> 2), g = (int)(j & 3);
        int r = g * DEC + d;
        bgr[j] = b_ih[r] + b_hh[r];
        return;
    }
    long m = j - G4;
    if (m < (long)DEC * VOCAB) {
        int k = (int)(m / VOCAB), v = (int)(m % VOCAB);
        WoutT[m] = W_out[(long)v * DEC + k];
        return;
    }
    long p = m - (long)DEC * VOCAB;
    if (p < (long)DEC * ATTN) {
        int k = (int)(p / ATTN), a = (int)(p % ATTN);
        WdT[p] = W_dec[(long)a * DEC + k];
    }
}

// ---------------- one-time init: flags=0, c0=c1=0, Xcat=[emb(SOS)|0|0] ----------------
__global__ void k_init(const float* __restrict__ emb_table,
                       float* __restrict__ c0, float* __restrict__ c1,
                       float* __restrict__ Xcat, int* __restrict__ flags) {
    long i = (long)blockIdx.x * 256 + threadIdx.x;
    if (i < BS * 16) flags[i] = 0;
    if (i < BS * DEC) { c0[i] = 0.f; c1[i] = 0.f; return; }
    long j = i - BS * DEC;
    if (j < (long)BS * KCAT) {
        int cdx = (int)(j % KCAT);
        Xcat[j] = (cdx < EMB) ? emb_table[cdx] : 0.f;  // SOS = row 0
    }
}

// ---------------- weighted_enc TRANSPOSED f32: weT[b,l,a] ----------------
__global__ __launch_bounds__(256) void k_wenc(const float* __restrict__ W_enc,
                                              const float* __restrict__ b_enc,
                                              const float* __restrict__ enc_out,
                                              float* __restrict__ weT) {
    __shared__ float As[16][68];
    __shared__ float Bs[16][68];
    int b = blockIdx.z;
    int a0 = blockIdx.y * 64;
    int l0 = blockIdx.x * 64;
    int t = threadIdx.x;
    int ty = t >> 4, tx = t & 15;
    float acc[4][4] = {};
    for (int e0 = 0; e0 < ENC; e0 += 16) {
        {
            int ar = t >> 2;
            int kg = (t & 3) << 2;
            float4 w4 = *(const float4*)&W_enc[(size_t)(a0 + ar) * ENC + e0 + kg];
            As[kg + 0][ar] = w4.x; As[kg + 1][ar] = w4.y; As[kg + 2][ar] = w4.z; As[kg + 3][ar] = w4.w;
            int er = t >> 4;
            int lg = (t & 15) << 2;
            float4 x4 = *(const float4*)&enc_out[((size_t)b * ENC + e0 + er) * L + l0 + lg];
            *(float4*)&Bs[er][lg] = x4;
        }
        __syncthreads();
        #pragma unroll
        for (int kk = 0; kk < 16; kk++) {
            float4 a4 = *(const float4*)&As[kk][ty * 4];
            float4 x4 = *(const float4*)&Bs[kk][tx * 4];
            float av[4] = {a4.x, a4.y, a4.z, a4.w};
            float xv[4] = {x4.x, x4.y, x4.z, x4.w};
            #pragma unroll
            for (int i = 0; i < 4; i++)
                #pragma unroll
                for (int j = 0; j < 4; j++) acc[i][j] += av[i] * xv[j];
        }
        __syncthreads();
    }
    float be0 = b_enc[a0 + ty * 4 + 0];
    float be1 = b_enc[a0 + ty * 4 + 1];
    float be2 = b_enc[a0 + ty * 4 + 2];
    float be3 = b_enc[a0 + ty * 4 + 3];
    #pragma unroll
    for (int j = 0; j < 4; j++) {
        int l = l0 + tx * 4 + j;
        float4 o = {acc[0][j] + be0, acc[1][j] + be1, acc[2][j] + be2, acc[3][j] + be3};
        *(float4*)&weT[((size_t)b * L + l) * ATTN + a0 + ty * 4] = o;
    }
}

// ---------------- fused out(ts-1)+attn(ts): 2 blocks per b (h = half), 512 threads ----------------
// c double-buffered; logits split across pair (bit-identical combine at h0 tail).
// ts==0: skip out-part (wd=b_dec). ts==TMAX: out-part only (full logits in-block).
__global__ __launch_bounds__(512) void k_aof(const float* __restrict__ gpart,
                                             const float* __restrict__ bgr,
                                             const float* __restrict__ WoutT,
                                             const float* __restrict__ b_out,
                                             const float* __restrict__ emb_table,
                                             const float* __restrict__ WdT,
                                             const float* __restrict__ b_dec,
                                             const float* __restrict__ c_in,
                                             float* __restrict__ c_out,
                                             float* __restrict__ logp_out,
                                             float* __restrict__ preds_out,
                                             float* __restrict__ Xcat,
                                             const float* __restrict__ weT,
                                             const float* __restrict__ v_e,
                                             const float* __restrict__ b_e,
                                             const float* __restrict__ enc_out,
                                             float* __restrict__ attn_out,
                                             float* __restrict__ scp,
                                             float* __restrict__ lp2,
                                             int* __restrict__ flags, int ts) {
    __shared__ float hs[DEC];
    __shared__ float wd_l[256];
    __shared__ float vel[256];
    __shared__ float al[L];
    __shared__ float red[512];
    __shared__ float rv[128];
    __shared__ int ri[128];
    __shared__ float redw[256][2];
    int b = blockIdx.x >> 1, h = blockIdx.x & 1;
    int t = threadIdx.x;
    int* flag = flags + b * 16;

    if (ts > 0) {
        // ===== out-part for step ts-1 (cell from c_in -> c_out, own-half writes) =====
        #pragma unroll
        for (int q = 0; q < 2; q++) {
            int d = q * 512 + t;
            const float* gp = gpart + (size_t)b * G4 + d * 4;
            float4 g = *(const float4*)gp;
            #pragma unroll
            for (int ks = 1; ks < 4; ks++) {
                float4 p = *(const float4*)(gp + (size_t)ks * BS * G4);
                g.x += p.x; g.y += p.y; g.z += p.z; g.w += p.w;
            }
            float4 bb = *(const float4*)&bgr[(size_t)d * 4];
            float gi = g.x + bb.x, gf = g.y + bb.y, gg = g.z + bb.z, go = g.w + bb.w;
            float fi = 1.f / (1.f + expf(-gi));
            float ff = 1.f / (1.f + expf(-gf));
            float fg = tanhf(gg);
            float fo = 1.f / (1.f + expf(-go));
            size_t ix = (size_t)b * DEC + d;
            float cn = ff * c_in[ix] + fi * fg;
            float hn = fo * tanhf(cn);
            if (q == h) {  // own half only: disjoint writes across the pair
                c_out[ix] = cn;
                Xcat[(size_t)b * KCAT + EMB + ENC + d] = hn;
            }
            hs[d] = hn;
        }
        __syncthreads();
        if (ts == TMAX) {  // epilogue: full logits on h0 (no pairsync available)
            if (h == 0) {
                int v = t & 127, kh = t >> 7;
                const float* wp = WoutT + (size_t)kh * 256 * VOCAB + v;
                float acc = 0.f;
                #pragma unroll 8
                for (int k = 0; k < 256; k++) acc += wp[(size_t)k * VOCAB] * hs[kh * 256 + k];
                red[t] = acc;
                __syncthreads();
                float logits = 0.f;
                if (t < 128) {
                    logits = ((red[t] + red[t + 128]) + (red[t + 256] + red[t + 384])) + b_out[t];
                    rv[t] = logits; ri[t] = t;
                }
                __syncthreads();
                for (int s = 64; s; s >>= 1) {
                    if (t < s) {
                        float ov = rv[t + s]; int oi = ri[t + s];
                        if (ov > rv[t] || (ov == rv[t] && oi < ri[t])) { rv[t] = ov; ri[t] = oi; }
                    }
                    __syncthreads();
                }
                float m = rv[0]; int am = ri[0];
                __syncthreads();
                if (t < 128) red[t] = expf(logits - m);
                __syncthreads();
                for (int s = 64; s; s >>= 1) { if (t < s && t + s < 128) red[t] += red[t + s]; __syncthreads(); }
                if (t < 128) logp_out[((size_t)b * TMAX + (ts - 1)) * VOCAB + t] = logits - m - logf(red[0]);
                if (t == 0) preds_out[(size_t)b * TMAX + (ts - 1)] = (float)am;
            }
            return;
        }
        // ===== logits partial for own k-half: quarters 2h, 2h+1 (R20-identical per-quarter sums) =====
        if (t < 256) {
            int v = t & 127, kq = t >> 7;              // kq in {0,1}
            int kh = 2 * h + kq;                        // global quarter
            const float* wp = WoutT + (size_t)kh * 256 * VOCAB + v;
            float acc = 0.f;
            #pragma unroll 8
            for (int k = 0; k < 256; k++) acc += wp[(size_t)k * VOCAB] * hs[kh * 256 + k];
            red[t] = acc;                               // red[v + kq*128]
        }
        __syncthreads();
        if (t < 128) lp2[((size_t)h * BS + b) * VOCAB + t] = red[t] + red[t + 128];  // p_h = r_{2h}+r_{2h+1}
        // wdec own a-half into LDS: a = h*256 + (t>>1), 2-way k-split (R20-verbatim)
        {
            int a_l = t >> 1, ksub = t & 1;
            int a = h * 256 + a_l;
            const float* wdp = WdT + (size_t)(ksub * 512) * ATTN + a;
            float s = 0.f;
            #pragma unroll 16
            for (int k = 0; k < 512; k++) s += wdp[(size_t)k * ATTN] * hs[ksub * 512 + k];
            redw[a_l][ksub] = s;
        }
        __syncthreads();
        if (t < 256) {
            wd_l[t] = (redw[t][0] + redw[t][1]) + b_dec[h * 256 + t];
            vel[t] = v_e[h * 256 + t];
        }
    } else {
        if (t < 256) {
            wd_l[t] = b_dec[h * 256 + t];  // h0 = 0
            vel[t] = v_e[h * 256 + t];
        }
    }
    __syncthreads();

    // ===== score partials over own a-half, ALL 512 rows (R20-verbatim) =====
    {
        int ah = t & 1;
        #pragma unroll
        for (int rr = 0; rr < 2; rr++) {
            int l = rr * 256 + (t >> 1);
            const float* row = weT + ((size_t)b * L + l) * ATTN + h * 256 + ah * 128;
            float acc = 0.f;
            #pragma unroll 8
            for (int a4 = 0; a4 < 128; a4 += 4) {
                float4 x = *(const float4*)&row[a4];
                int a = ah * 128 + a4;
                acc += vel[a + 0] * tanh_fast(x.x + wd_l[a + 0]);
                acc += vel[a + 1] * tanh_fast(x.y + wd_l[a + 1]);
                acc += vel[a + 2] * tanh_fast(x.z + wd_l[a + 2]);
                acc += vel[a + 3] * tanh_fast(x.w + wd_l[a + 3]);
            }
            acc += __shfl_xor(acc, 1, 64);
            if (ah == 0) scp[((size_t)h * BS + b) * L + l] = acc;
        }
    }
    pairsync(flag, 2 * (ts + 1));  // ONE pairsync per step

    // ===== combine + softmax over 512 (R20-verbatim tree) =====
    float sc = scp[(size_t)b * L + t] + scp[((size_t)BS + b) * L + t] + b_e[0];
    red[t] = sc;
    __syncthreads();
    for (int s = 256; s; s >>= 1) { if (t < s) red[t] = fmaxf(red[t], red[t + s]); __syncthreads(); }
    float m = red[0];
    __syncthreads();
    float e = expf(sc - m);
    red[t] = e;
    __syncthreads();
    for (int s = 256; s; s >>= 1) { if (t < s) red[t] += red[t + s]; __syncthreads(); }
    float inv = 1.f / red[0];
    al[t] = e * inv;
    __syncthreads();
    if (h == 0) attn_out[((size_t)b * TMAX + ts) * L + t] = al[t];

    // ===== context for own e-half: 256 rows, 2 threads/row (R20-verbatim) =====
    {
        int r2 = t >> 1, lh2 = (t & 1) * 256;
        int e_ = h * 256 + r2;
        const float* erow = enc_out + ((size_t)b * ENC + e_) * L + lh2;
        float cacc = 0.f;
        #pragma unroll 8
        for (int l4 = 0; l4 < 256; l4 += 4) {
            float4 x = *(const float4*)&erow[l4];
            float4 a4 = *(const float4*)&al[lh2 + l4];
            cacc += x.x * a4.x + x.y * a4.y + x.z * a4.z + x.w * a4.w;
        }
        cacc += __shfl_xor(cacc, 1, 64);
        if ((t & 1) == 0) Xcat[(size_t)b * KCAT + EMB + e_] = cacc;
    }

    // ===== h0 tail: combine logit partials (bit-identical to R20), argmax, logp, emb =====
    if (h == 0 && ts > 0) {
        __syncthreads();  // red reuse (uniform branch: h,ts uniform per block)
        float logits = 0.f;
        if (t < 128) {
            logits = (lp2[(size_t)b * VOCAB + t] + lp2[((size_t)BS + b) * VOCAB + t]) + b_out[t];
            rv[t] = logits; ri[t] = t;
        }
        __syncthreads();
        for (int s = 64; s; s >>= 1) {
            if (t < s) {
                float ov = rv[t + s]; int oi = ri[t + s];
                if (ov > rv[t] || (ov == rv[t] && oi < ri[t])) { rv[t] = ov; ri[t] = oi; }
            }
            __syncthreads();
        }
        float m2 = rv[0]; int am = ri[0];
        __syncthreads();
        if (t < 128) red[t] = expf(logits - m2);
        __syncthreads();
        for (int s = 64; s; s >>= 1) { if (t < s && t + s < 128) red[t] += red[t + s]; __syncthreads(); }
        if (t < 128) logp_out[((size_t)b * TMAX + (ts - 1)) * VOCAB + t] = logits - m2 - logf(red[0]);
        if (t == 0) preds_out[(size_t)b * TMAX + (ts - 1)] = (float)am;
        if (t < 256) Xcat[(size_t)b * KCAT + t] = emb_table[(size_t)am * EMB + t];
    }
}

// ---------------- gates GEMM partials: K-split x4, b-split x4 (32-b tiles) — R20-verbatim ----------------
__global__ __launch_bounds__(256) void k_gates(const float* __restrict__ Wgr,
                                               const float* __restrict__ Xcat,
                                               float* __restrict__ gates_part) {
    __shared__ float As[16][68];  // [k][m'] 64 rows
    __shared__ float Xs[16][36];  // [k][b]  32 cols
    int M0 = blockIdx.x * 64;
    int b0 = blockIdx.y * 32;
    int ks = blockIdx.z;
    int kbase = ks * 448, kend = kbase + 448;
    int t = threadIdx.x, ty = t >> 4, tx = t & 15;
    int r = t >> 2, kg = (t & 3) << 2;
    float acc[4][2] = {};
    float4 wreg = *(const float4*)&Wgr[(size_t)(M0 + r) * KCAT + kbase + kg];
    float4 xreg;
    if (t < 128) xreg = *(const float4*)&Xcat[(size_t)(b0 + r) * KCAT + kbase + kg];
    for (int k0 = kbase; k0 < kend; k0 += 16) {
        As[kg + 0][r] = wreg.x; As[kg + 1][r] = wreg.y; As[kg + 2][r] = wreg.z; As[kg + 3][r] = wreg.w;
        if (t < 128) {
            Xs[kg + 0][r] = xreg.x; Xs[kg + 1][r] = xreg.y; Xs[kg + 2][r] = xreg.z; Xs[kg + 3][r] = xreg.w;
        }
        __syncthreads();
        if (k0 + 16 < kend) {
            wreg = *(const float4*)&Wgr[(size_t)(M0 + r) * KCAT + k0 + 16 + kg];
            if (t < 128) xreg = *(const float4*)&Xcat[(size_t)(b0 + r) * KCAT + k0 + 16 + kg];
        }
        #pragma unroll
        for (int kk = 0; kk < 16; kk++) {
            float4 a4 = *(const float4*)&As[kk][ty * 4];
            float xb0 = Xs[kk][tx * 2], xb1 = Xs[kk][tx * 2 + 1];
            acc[0][0] += a4.x * xb0; acc[0][1] += a4.x * xb1;
            acc[1][0] += a4.y * xb0; acc[1][1] += a4.y * xb1;
            acc[2][0] += a4.z * xb0; acc[2][1] += a4.z * xb1;
            acc[3][0] += a4.w * xb0; acc[3][1] += a4.w * xb1;
        }
        __syncthreads();
    }
    float* gp = gates_part + (size_t)ks * BS * G4;
    #pragma unroll
    for (int j = 0; j < 2; j++) {
        float4 o = {acc[0][j], acc[1][j], acc[2][j], acc[3][j]};
        *(float4*)&gp[(size_t)(b0 + tx * 2 + j) * G4 + M0 + ty * 4] = o;
    }
}

extern "C" void kernel_launch(void* const* d_in, const int* in_sizes, int n_in,
                              void* d_out, int out_size, void* d_ws, size_t ws_size,
                              hipStream_t stream) {
    const float* enc_out = (const float*)d_in[0];
    const float* W_enc   = (const float*)d_in[1];
    const float* b_enc   = (const float*)d_in[2];
    const float* W_dec   = (const float*)d_in[3];
    const float* b_dec   = (const float*)d_in[4];
    const float* v_e     = (const float*)d_in[5];
    const float* b_e     = (const float*)d_in[6];
    const float* emb     = (const float*)d_in[7];
    const float* W_ih    = (const float*)d_in[8];
    const float* W_hh    = (const float*)d_in[9];
    const float* b_ih    = (const float*)d_in[10];
    const float* b_hh    = (const float*)d_in[11];
    const float* W_out   = (const float*)d_in[12];
    const float* b_out   = (const float*)d_in[13];

    float* ws    = (float*)d_ws;
    float* weT   = ws + OFF_WET;
    float* Wgr   = ws + OFF_WGR;
    float* bgr   = ws + OFF_BGR;
    float* WoutT = ws + OFF_WOUTT;
    float* WdT   = ws + OFF_WDT;
    float* c0    = ws + OFF_C0;
    float* c1    = ws + OFF_C1;
    float* scp   = ws + OFF_SCP;
    float* lp2   = ws + OFF_LP2;
    float* Xcat  = ws + OFF_XCAT;
    float* gpart = ws + OFF_GPART;
    int*   flags = (int*)(ws + OFF_FLAG);

    float* logp_out  = (float*)d_out;
    float* preds_out = logp_out + (size_t)BS * TMAX * VOCAB;
    float* attn_out  = preds_out + (size_t)BS * TMAX;

    {
        long n = (long)G4 * KCAT + G4 + (long)DEC * VOCAB + (long)DEC * ATTN;
        k_prep<<<(int)((n + 255) / 256), 256, 0, stream>>>(W_ih, W_hh, b_ih, b_hh, W_out, W_dec,
                                                           Wgr, bgr, WoutT, WdT);
    }
    {
        long n = (long)BS * DEC + (long)BS * KCAT;
        k_init<<<(int)((n + 255) / 256), 256, 0, stream>>>(emb, c0, c1, Xcat, flags);
    }
    k_wenc<<<dim3(8, 8, 128), 256, 0, stream>>>(W_enc, b_enc, enc_out, weT);

    for (int t = 0; t < TMAX; t++) {
        float* cin  = (t & 1) ? c1 : c0;
        float* cout = (t & 1) ? c0 : c1;
        k_aof<<<256, 512, 0, stream>>>(gpart, bgr, WoutT, b_out, emb, WdT, b_dec,
                                       cin, cout, logp_out, preds_out, Xcat, weT,
                                       v_e, b_e, enc_out, attn_out, scp, lp2, flags, t);
        k_gates<<<dim3(64, 4, 4), 256, 0, stream>>>(Wgr, Xcat, gpart);
    }
    // epilogue: out-part for step TMAX-1 (c_in = c0 since TMAX is even)
    k_aof<<<256, 512, 0, stream>>>(gpart, bgr, WoutT, b_out, emb, WdT, b_dec,
                                   c0, c1, logp_out, preds_out, Xcat, weT,
                                   v_e, b_e, enc_out, attn_out, scp, lp2, flags, TMAX);
}

// Round 22
// 18366.991 us; speedup vs baseline: 1.0764x; 1.0764x over previous
//
#include <hip/hip_runtime.h>
#include <math.h>

#define BS 128
#define L 512
#define ENC 512
#define DEC 1024
#define ATTN 512
#define EMB 256
#define VOCAB 128
#define TMAX 128
#define KCAT 1792  // EMB+ENC+DEC
#define G4 4096    // 4*DEC

// ---- workspace layout (float offsets) ----
#define OFF_WET    0ull                       // [BS][L][ATTN]     33554432
#define OFF_WGR    33554432ull                // [G4][KCAT] d-major 7340032
#define OFF_BGR    40894464ull                // [G4] d-major          4096
#define OFF_WOUTT  40898560ull                // [DEC][VOCAB]        131072
#define OFF_WDT    41029632ull                // [DEC][ATTN]         524288
#define OFF_C0     41553920ull                // [BS][DEC]           131072
#define OFF_C1     41684992ull                // [BS][DEC]           131072
#define OFF_SCP    41816064ull                // [2][BS][L] partials 131072
#define OFF_XCAT   41947136ull                // [BS][KCAT]          229376
#define OFF_GPART  42176512ull                // [4][BS][G4]        2097152
#define OFF_FLAG   44273664ull                // [BS*16] pair flags    2048
// end: 44275712 floats = 177.1 MB

// branch-free tanh: exp + Newton-refined rcp, ~3e-7 rel err
__device__ __forceinline__ float tanh_fast(float x) {
    float ax = fabsf(x);
    float e = __expf(-2.f * ax);
    float d = 1.f + e;
    float r = __builtin_amdgcn_rcpf(d);
    r = r * (2.f - d * r);
    float t = 1.f - 2.f * e * r;
    return copysignf(t, x);
}

// 2-block pair barrier: monotonic counter, relaxed spin (2 pollers/line)
__device__ __forceinline__ void pairsync(int* flag, int target) {
    __syncthreads();
    if (threadIdx.x == 0) {
        __threadfence();  // release prior global writes
        __hip_atomic_fetch_add(flag, 1, __ATOMIC_ACQ_REL, __HIP_MEMORY_SCOPE_AGENT);
        while (__hip_atomic_load(flag, __ATOMIC_RELAXED, __HIP_MEMORY_SCOPE_AGENT) < target) {
            __builtin_amdgcn_s_sleep(4);
        }
        __threadfence();  // acquire partner's writes
    }
    __syncthreads();
}

// ---------------- one-time prep: d-major W_gate concat, bias sum, W_out^T, W_dec^T ----------------
__global__ void k_prep(const float* __restrict__ W_ih, const float* __restrict__ W_hh,
                       const float* __restrict__ b_ih, const float* __restrict__ b_hh,
                       const float* __restrict__ W_out, const float* __restrict__ W_dec,
                       float* __restrict__ Wgr, float* __restrict__ bgr,
                       float* __restrict__ WoutT, float* __restrict__ WdT) {
    long i = (long)blockIdx.x * 256 + threadIdx.x;
    if (i < (long)G4 * KCAT) {
        int mp = (int)(i / KCAT), k = (int)(i % KCAT);
        int d = mp >> 2, g = mp & 3;
        int r = g * DEC + d;
        Wgr[i] = (k < EMB + ENC) ? W_ih[(long)r * (EMB + ENC) + k]
                                 : W_hh[(long)r * DEC + (k - (EMB + ENC))];
        return;
    }
    long j = i - (long)G4 * KCAT;
    if (j < G4) {
        int d = (int)(j >> 2), g = (int)(j & 3);
        int r = g * DEC + d;
        bgr[j] = b_ih[r] + b_hh[r];
        return;
    }
    long m = j - G4;
    if (m < (long)DEC * VOCAB) {
        int k = (int)(m / VOCAB), v = (int)(m % VOCAB);
        WoutT[m] = W_out[(long)v * DEC + k];
        return;
    }
    long p = m - (long)DEC * VOCAB;
    if (p < (long)DEC * ATTN) {
        int k = (int)(p / ATTN), a = (int)(p % ATTN);
        WdT[p] = W_dec[(long)a * DEC + k];
    }
}

// ---------------- one-time init: flags=0, c0=c1=0, Xcat=[emb(SOS)|0|0] ----------------
__global__ void k_init(const float* __restrict__ emb_table,
                       float* __restrict__ c0, float* __restrict__ c1,
                       float* __restrict__ Xcat, int* __restrict__ flags) {
    long i = (long)blockIdx.x * 256 + threadIdx.x;
    if (i < BS * 16) flags[i] = 0;
    if (i < BS * DEC) { c0[i] = 0.f; c1[i] = 0.f; return; }
    long j = i - BS * DEC;
    if (j < (long)BS * KCAT) {
        int cdx = (int)(j % KCAT);
        Xcat[j] = (cdx < EMB) ? emb_table[cdx] : 0.f;  // SOS = row 0
    }
}

// ---------------- weighted_enc TRANSPOSED f32: weT[b,l,a] ----------------
__global__ __launch_bounds__(256) void k_wenc(const float* __restrict__ W_enc,
                                              const float* __restrict__ b_enc,
                                              const float* __restrict__ enc_out,
                                              float* __restrict__ weT) {
    __shared__ float As[16][68];
    __shared__ float Bs[16][68];
    int b = blockIdx.z;
    int a0 = blockIdx.y * 64;
    int l0 = blockIdx.x * 64;
    int t = threadIdx.x;
    int ty = t >> 4, tx = t & 15;
    float acc[4][4] = {};
    for (int e0 = 0; e0 < ENC; e0 += 16) {
        {
            int ar = t >> 2;
            int kg = (t & 3) << 2;
            float4 w4 = *(const float4*)&W_enc[(size_t)(a0 + ar) * ENC + e0 + kg];
            As[kg + 0][ar] = w4.x; As[kg + 1][ar] = w4.y; As[kg + 2][ar] = w4.z; As[kg + 3][ar] = w4.w;
            int er = t >> 4;
            int lg = (t & 15) << 2;
            float4 x4 = *(const float4*)&enc_out[((size_t)b * ENC + e0 + er) * L + l0 + lg];
            *(float4*)&Bs[er][lg] = x4;
        }
        __syncthreads();
        #pragma unroll
        for (int kk = 0; kk < 16; kk++) {
            float4 a4 = *(const float4*)&As[kk][ty * 4];
            float4 x4 = *(const float4*)&Bs[kk][tx * 4];
            float av[4] = {a4.x, a4.y, a4.z, a4.w};
            float xv[4] = {x4.x, x4.y, x4.z, x4.w};
            #pragma unroll
            for (int i = 0; i < 4; i++)
                #pragma unroll
                for (int j = 0; j < 4; j++) acc[i][j] += av[i] * xv[j];
        }
        __syncthreads();
    }
    float be0 = b_enc[a0 + ty * 4 + 0];
    float be1 = b_enc[a0 + ty * 4 + 1];
    float be2 = b_enc[a0 + ty * 4 + 2];
    float be3 = b_enc[a0 + ty * 4 + 3];
    #pragma unroll
    for (int j = 0; j < 4; j++) {
        int l = l0 + tx * 4 + j;
        float4 o = {acc[0][j] + be0, acc[1][j] + be1, acc[2][j] + be2, acc[3][j] + be3};
        *(float4*)&weT[((size_t)b * L + l) * ATTN + a0 + ty * 4] = o;
    }
}

// ---------------- fused out(ts-1)+attn(ts): 2 blocks per b (h = half), 512 threads ----------------
// c double-buffered: both read c_in, block h writes its d-half of c_out (race-free, no sync).
// ts==0: skip out-part (wd=b_dec). ts==TMAX: out-part only.
__global__ __launch_bounds__(512) void k_aof(const float* __restrict__ gpart,
                                             const float* __restrict__ bgr,
                                             const float* __restrict__ WoutT,
                                             const float* __restrict__ b_out,
                                             const float* __restrict__ emb_table,
                                             const float* __restrict__ WdT,
                                             const float* __restrict__ b_dec,
                                             const float* __restrict__ c_in,
                                             float* __restrict__ c_out,
                                             float* __restrict__ logp_out,
                                             float* __restrict__ preds_out,
                                             float* __restrict__ Xcat,
                                             const float* __restrict__ weT,
                                             const float* __restrict__ v_e,
                                             const float* __restrict__ b_e,
                                             const float* __restrict__ enc_out,
                                             float* __restrict__ attn_out,
                                             float* __restrict__ scp,
                                             int* __restrict__ flags, int ts) {
    __shared__ float hs[DEC];
    __shared__ float wd_l[256];
    __shared__ float vel[256];
    __shared__ float al[L];
    __shared__ float red[512];
    __shared__ float rv[128];
    __shared__ int ri[128];
    __shared__ float redw[256][2];
    int b = blockIdx.x >> 1, h = blockIdx.x & 1;
    int t = threadIdx.x;
    int* flag = flags + b * 16;

    if (ts > 0) {
        // ===== out-part for step ts-1 (cell from c_in -> c_out, own-half writes) =====
        #pragma unroll
        for (int q = 0; q < 2; q++) {
            int d = q * 512 + t;
            const float* gp = gpart + (size_t)b * G4 + d * 4;
            float4 g = *(const float4*)gp;
            #pragma unroll
            for (int ks = 1; ks < 4; ks++) {
                float4 p = *(const float4*)(gp + (size_t)ks * BS * G4);
                g.x += p.x; g.y += p.y; g.z += p.z; g.w += p.w;
            }
            float4 bb = *(const float4*)&bgr[(size_t)d * 4];
            float gi = g.x + bb.x, gf = g.y + bb.y, gg = g.z + bb.z, go = g.w + bb.w;
            float fi = 1.f / (1.f + expf(-gi));
            float ff = 1.f / (1.f + expf(-gf));
            float fg = tanhf(gg);
            float fo = 1.f / (1.f + expf(-go));
            size_t ix = (size_t)b * DEC + d;
            float cn = ff * c_in[ix] + fi * fg;
            float hn = fo * tanhf(cn);
            if (q == h) {  // own half only: disjoint writes across the pair
                c_out[ix] = cn;
                Xcat[(size_t)b * KCAT + EMB + ENC + d] = hn;
            }
            hs[d] = hn;
        }
        __syncthreads();
        if (h == 0) {
            // logits: 4-way K split (span 256), verbatim R20 order
            int v = t & 127, kh = t >> 7;
            const float* wp = WoutT + (size_t)kh * 256 * VOCAB + v;
            float acc = 0.f;
            #pragma unroll 8
            for (int k = 0; k < 256; k++) acc += wp[(size_t)k * VOCAB] * hs[kh * 256 + k];
            red[t] = acc;
            __syncthreads();
            float logits = 0.f;
            if (t < 128) {
                logits = ((red[t] + red[t + 128]) + (red[t + 256] + red[t + 384])) + b_out[t];
                rv[t] = logits; ri[t] = t;
            }
            __syncthreads();
            for (int s = 64; s; s >>= 1) {
                if (t < s) {
                    float ov = rv[t + s]; int oi = ri[t + s];
                    if (ov > rv[t] || (ov == rv[t] && oi < ri[t])) { rv[t] = ov; ri[t] = oi; }
                }
                __syncthreads();
            }
            float m = rv[0]; int am = ri[0];
            __syncthreads();
            if (t < 128) red[t] = expf(logits - m);
            __syncthreads();
            for (int s = 64; s; s >>= 1) { if (t < s && t + s < 128) red[t] += red[t + s]; __syncthreads(); }
            if (t < 128) logp_out[((size_t)b * TMAX + (ts - 1)) * VOCAB + t] = logits - m - logf(red[0]);
            if (t == 0) preds_out[(size_t)b * TMAX + (ts - 1)] = (float)am;
            if (t < 256) Xcat[(size_t)b * KCAT + t] = emb_table[(size_t)am * EMB + t];
        }
        if (ts == TMAX) return;  // epilogue: out only
        // wdec own a-half into LDS: a = h*256 + (t>>1), 2-way k-split (R20-verbatim)
        {
            int a_l = t >> 1, ksub = t & 1;
            int a = h * 256 + a_l;
            const float* wdp = WdT + (size_t)(ksub * 512) * ATTN + a;
            float s = 0.f;
            #pragma unroll 16
            for (int k = 0; k < 512; k++) s += wdp[(size_t)k * ATTN] * hs[ksub * 512 + k];
            redw[a_l][ksub] = s;
        }
        __syncthreads();
        if (t < 256) {
            wd_l[t] = (redw[t][0] + redw[t][1]) + b_dec[h * 256 + t];
            vel[t] = v_e[h * 256 + t];
        }
    } else {
        if (t < 256) {
            wd_l[t] = b_dec[h * 256 + t];  // h0 = 0
            vel[t] = v_e[h * 256 + t];
        }
    }
    __syncthreads();

    // ===== score partials over own a-half, ALL 512 rows (R20-verbatim) =====
    {
        int ah = t & 1;
        #pragma unroll
        for (int rr = 0; rr < 2; rr++) {
            int l = rr * 256 + (t >> 1);
            const float* row = weT + ((size_t)b * L + l) * ATTN + h * 256 + ah * 128;
            float acc = 0.f;
            #pragma unroll 8
            for (int a4 = 0; a4 < 128; a4 += 4) {
                float4 x = *(const float4*)&row[a4];
                int a = ah * 128 + a4;
                acc += vel[a + 0] * tanh_fast(x.x + wd_l[a + 0]);
                acc += vel[a + 1] * tanh_fast(x.y + wd_l[a + 1]);
                acc += vel[a + 2] * tanh_fast(x.z + wd_l[a + 2]);
                acc += vel[a + 3] * tanh_fast(x.w + wd_l[a + 3]);
            }
            acc += __shfl_xor(acc, 1, 64);
            if (ah == 0) scp[((size_t)h * BS + b) * L + l] = acc;
        }
    }
    pairsync(flag, 2 * (ts + 1));  // ONE pairsync per step

    // ===== combine + softmax over 512 (R20-verbatim tree) =====
    float sc = scp[(size_t)b * L + t] + scp[((size_t)BS + b) * L + t] + b_e[0];
    red[t] = sc;
    __syncthreads();
    for (int s = 256; s; s >>= 1) { if (t < s) red[t] = fmaxf(red[t], red[t + s]); __syncthreads(); }
    float m = red[0];
    __syncthreads();
    float e = expf(sc - m);
    red[t] = e;
    __syncthreads();
    for (int s = 256; s; s >>= 1) { if (t < s) red[t] += red[t + s]; __syncthreads(); }
    float inv = 1.f / red[0];
    al[t] = e * inv;
    __syncthreads();
    if (h == 0) attn_out[((size_t)b * TMAX + ts) * L + t] = al[t];

    // ===== context for own e-half: 256 rows, 2 threads/row (R20-verbatim) =====
    {
        int r2 = t >> 1, lh2 = (t & 1) * 256;
        int e_ = h * 256 + r2;
        const float* erow = enc_out + ((size_t)b * ENC + e_) * L + lh2;
        float cacc = 0.f;
        #pragma unroll 8
        for (int l4 = 0; l4 < 256; l4 += 4) {
            float4 x = *(const float4*)&erow[l4];
            float4 a4 = *(const float4*)&al[lh2 + l4];
            cacc += x.x * a4.x + x.y * a4.y + x.z * a4.z + x.w * a4.w;
        }
        cacc += __shfl_xor(cacc, 1, 64);
        if ((t & 1) == 0) Xcat[(size_t)b * KCAT + EMB + e_] = cacc;
    }
}

// ---------------- gates GEMM partials: K-split x4, b-split x2 (64-b tiles, R13-proven) ----------------
// grid (64, 2, 4): 64 m'-rows x 64 b x 448 K per block -> gpart[ks][b][m']
__global__ __launch_bounds__(256) void k_gates(const float* __restrict__ Wgr,
                                               const float* __restrict__ Xcat,
                                               float* __restrict__ gates_part) {
    __shared__ float As[16][68];
    __shared__ float Xs[16][68];
    int M0 = blockIdx.x * 64;
    int b0 = blockIdx.y * 64;
    int ks = blockIdx.z;
    int kbase = ks * 448, kend = kbase + 448;
    int t = threadIdx.x, ty = t >> 4, tx = t & 15;
    int r = t >> 2, kg = (t & 3) << 2;
    float acc[4][4] = {};
    float4 wreg = *(const float4*)&Wgr[(size_t)(M0 + r) * KCAT + kbase + kg];
    float4 xreg = *(const float4*)&Xcat[(size_t)(b0 + r) * KCAT + kbase + kg];
    for (int k0 = kbase; k0 < kend; k0 += 16) {
        As[kg + 0][r] = wreg.x; As[kg + 1][r] = wreg.y; As[kg + 2][r] = wreg.z; As[kg + 3][r] = wreg.w;
        Xs[kg + 0][r] = xreg.x; Xs[kg + 1][r] = xreg.y; Xs[kg + 2][r] = xreg.z; Xs[kg + 3][r] = xreg.w;
        __syncthreads();
        if (k0 + 16 < kend) {
            wreg = *(const float4*)&Wgr[(size_t)(M0 + r) * KCAT + k0 + 16 + kg];
            xreg = *(const float4*)&Xcat[(size_t)(b0 + r) * KCAT + k0 + 16 + kg];
        }
        #pragma unroll
        for (int kk = 0; kk < 16; kk++) {
            float4 a4 = *(const float4*)&As[kk][ty * 4];
            float4 x4 = *(const float4*)&Xs[kk][tx * 4];
            float av[4] = {a4.x, a4.y, a4.z, a4.w};
            float xv[4] = {x4.x, x4.y, x4.z, x4.w};
            #pragma unroll
            for (int i = 0; i < 4; i++)
                #pragma unroll
                for (int j = 0; j < 4; j++) acc[i][j] += av[i] * xv[j];
        }
        __syncthreads();
    }
    float* gp = gates_part + (size_t)ks * BS * G4;
    #pragma unroll
    for (int j = 0; j < 4; j++) {
        float4 o = {acc[0][j], acc[1][j], acc[2][j], acc[3][j]};
        *(float4*)&gp[(size_t)(b0 + tx * 4 + j) * G4 + M0 + ty * 4] = o;
    }
}

extern "C" void kernel_launch(void* const* d_in, const int* in_sizes, int n_in,
                              void* d_out, int out_size, void* d_ws, size_t ws_size,
                              hipStream_t stream) {
    const float* enc_out = (const float*)d_in[0];
    const float* W_enc   = (const float*)d_in[1];
    const float* b_enc   = (const float*)d_in[2];
    const float* W_dec   = (const float*)d_in[3];
    const float* b_dec   = (const float*)d_in[4];
    const float* v_e     = (const float*)d_in[5];
    const float* b_e     = (const float*)d_in[6];
    const float* emb     = (const float*)d_in[7];
    const float* W_ih    = (const float*)d_in[8];
    const float* W_hh    = (const float*)d_in[9];
    const float* b_ih    = (const float*)d_in[10];
    const float* b_hh    = (const float*)d_in[11];
    const float* W_out   = (const float*)d_in[12];
    const float* b_out   = (const float*)d_in[13];

    float* ws    = (float*)d_ws;
    float* weT   = ws + OFF_WET;
    float* Wgr   = ws + OFF_WGR;
    float* bgr   = ws + OFF_BGR;
    float* WoutT = ws + OFF_WOUTT;
    float* WdT   = ws + OFF_WDT;
    float* c0    = ws + OFF_C0;
    float* c1    = ws + OFF_C1;
    float* scp   = ws + OFF_SCP;
    float* Xcat  = ws + OFF_XCAT;
    float* gpart = ws + OFF_GPART;
    int*   flags = (int*)(ws + OFF_FLAG);

    float* logp_out  = (float*)d_out;
    float* preds_out = logp_out + (size_t)BS * TMAX * VOCAB;
    float* attn_out  = preds_out + (size_t)BS * TMAX;

    {
        long n = (long)G4 * KCAT + G4 + (long)DEC * VOCAB + (long)DEC * ATTN;
        k_prep<<<(int)((n + 255) / 256), 256, 0, stream>>>(W_ih, W_hh, b_ih, b_hh, W_out, W_dec,
                                                           Wgr, bgr, WoutT, WdT);
    }
    {
        long n = (long)BS * DEC + (long)BS * KCAT;
        k_init<<<(int)((n + 255) / 256), 256, 0, stream>>>(emb, c0, c1, Xcat, flags);
    }
    k_wenc<<<dim3(8, 8, 128), 256, 0, stream>>>(W_enc, b_enc, enc_out, weT);

    for (int t = 0; t < TMAX; t++) {
        float* cin  = (t & 1) ? c1 : c0;
        float* cout = (t & 1) ? c0 : c1;
        k_aof<<<256, 512, 0, stream>>>(gpart, bgr, WoutT, b_out, emb, WdT, b_dec,
                                       cin, cout, logp_out, preds_out, Xcat, weT,
                                       v_e, b_e, enc_out, attn_out, scp, flags, t);
        k_gates<<<dim3(64, 2, 4), 256, 0, stream>>>(Wgr, Xcat, gpart);
    }
    // epilogue: out-part for step TMAX-1 (c_in = c0 since TMAX is even)
    k_aof<<<256, 512, 0, stream>>>(gpart, bgr, WoutT, b_out, emb, WdT, b_dec,
                                   c0, c1, logp_out, preds_out, Xcat, weT,
                                   v_e, b_e, enc_out, attn_out, scp, flags, TMAX);
}

// Round 23
// 18333.406 us; speedup vs baseline: 1.0784x; 1.0018x over previous
//
#include <hip/hip_runtime.h>
#include <math.h>

#define BS 128
#define L 512
#define ENC 512
#define DEC 1024
#define ATTN 512
#define EMB 256
#define VOCAB 128
#define TMAX 128
#define KCAT 1792  // EMB+ENC+DEC
#define G4 4096    // 4*DEC

// ---- workspace layout (float offsets) ----
#define OFF_WET    0ull                       // [BS][L][ATTN]     33554432
#define OFF_WGR    33554432ull                // [G4][KCAT] d-major 7340032
#define OFF_BGR    40894464ull                // [G4] d-major          4096
#define OFF_WOUTT  40898560ull                // [DEC][VOCAB]        131072
#define OFF_WDT    41029632ull                // [DEC][ATTN]         524288
#define OFF_C0     41553920ull                // [BS][DEC]           131072
#define OFF_C1     41684992ull                // [BS][DEC]           131072
#define OFF_SCP    41816064ull                // [2][BS][L] partials 131072
#define OFF_XCAT   41947136ull                // [BS][KCAT]          229376
#define OFF_GPART  42176512ull                // [4][BS][G4]        2097152
#define OFF_FLAG   44273664ull                // [BS*16] pair flags    2048
// end: 44275712 floats = 177.1 MB

// branch-free tanh: exp + Newton-refined rcp, ~3e-7 rel err
__device__ __forceinline__ float tanh_fast(float x) {
    float ax = fabsf(x);
    float e = __expf(-2.f * ax);
    float d = 1.f + e;
    float r = __builtin_amdgcn_rcpf(d);
    r = r * (2.f - d * r);
    float t = 1.f - 2.f * e * r;
    return copysignf(t, x);
}

// 2-block pair barrier: monotonic counter, relaxed spin (2 pollers/line)
__device__ __forceinline__ void pairsync(int* flag, int target) {
    __syncthreads();
    if (threadIdx.x == 0) {
        __threadfence();  // release prior global writes
        __hip_atomic_fetch_add(flag, 1, __ATOMIC_ACQ_REL, __HIP_MEMORY_SCOPE_AGENT);
        while (__hip_atomic_load(flag, __ATOMIC_RELAXED, __HIP_MEMORY_SCOPE_AGENT) < target) {
            __builtin_amdgcn_s_sleep(4);
        }
        __threadfence();  // acquire partner's writes
    }
    __syncthreads();
}

// ---------------- one-time prep: d-major W_gate concat, bias sum, W_out^T, W_dec^T ----------------
__global__ void k_prep(const float* __restrict__ W_ih, const float* __restrict__ W_hh,
                       const float* __restrict__ b_ih, const float* __restrict__ b_hh,
                       const float* __restrict__ W_out, const float* __restrict__ W_dec,
                       float* __restrict__ Wgr, float* __restrict__ bgr,
                       float* __restrict__ WoutT, float* __restrict__ WdT) {
    long i = (long)blockIdx.x * 256 + threadIdx.x;
    if (i < (long)G4 * KCAT) {
        int mp = (int)(i / KCAT), k = (int)(i % KCAT);
        int d = mp >> 2, g = mp & 3;
        int r = g * DEC + d;
        Wgr[i] = (k < EMB + ENC) ? W_ih[(long)r * (EMB + ENC) + k]
                                 : W_hh[(long)r * DEC + (k - (EMB + ENC))];
        return;
    }
    long j = i - (long)G4 * KCAT;
    if (j < G4) {
        int d = (int)(j >> 2), g = (int)(j & 3);
        int r = g * DEC + d;
        bgr[j] = b_ih[r] + b_hh[r];
        return;
    }
    long m = j - G4;
    if (m < (long)DEC * VOCAB) {
        int k = (int)(m / VOCAB), v = (int)(m % VOCAB);
        WoutT[m] = W_out[(long)v * DEC + k];
        return;
    }
    long p = m - (long)DEC * VOCAB;
    if (p < (long)DEC * ATTN) {
        int k = (int)(p / ATTN), a = (int)(p % ATTN);
        WdT[p] = W_dec[(long)a * DEC + k];
    }
}

// ---------------- one-time init: flags=0, c0=c1=0, Xcat=[emb(SOS)|0|0] ----------------
__global__ void k_init(const float* __restrict__ emb_table,
                       float* __restrict__ c0, float* __restrict__ c1,
                       float* __restrict__ Xcat, int* __restrict__ flags) {
    long i = (long)blockIdx.x * 256 + threadIdx.x;
    if (i < BS * 16) flags[i] = 0;
    if (i < BS * DEC) { c0[i] = 0.f; c1[i] = 0.f; return; }
    long j = i - BS * DEC;
    if (j < (long)BS * KCAT) {
        int cdx = (int)(j % KCAT);
        Xcat[j] = (cdx < EMB) ? emb_table[cdx] : 0.f;  // SOS = row 0
    }
}

// ---------------- weighted_enc TRANSPOSED f32: weT[b,l,a] ----------------
__global__ __launch_bounds__(256) void k_wenc(const float* __restrict__ W_enc,
                                              const float* __restrict__ b_enc,
                                              const float* __restrict__ enc_out,
                                              float* __restrict__ weT) {
    __shared__ float As[16][68];
    __shared__ float Bs[16][68];
    int b = blockIdx.z;
    int a0 = blockIdx.y * 64;
    int l0 = blockIdx.x * 64;
    int t = threadIdx.x;
    int ty = t >> 4, tx = t & 15;
    float acc[4][4] = {};
    for (int e0 = 0; e0 < ENC; e0 += 16) {
        {
            int ar = t >> 2;
            int kg = (t & 3) << 2;
            float4 w4 = *(const float4*)&W_enc[(size_t)(a0 + ar) * ENC + e0 + kg];
            As[kg + 0][ar] = w4.x; As[kg + 1][ar] = w4.y; As[kg + 2][ar] = w4.z; As[kg + 3][ar] = w4.w;
            int er = t >> 4;
            int lg = (t & 15) << 2;
            float4 x4 = *(const float4*)&enc_out[((size_t)b * ENC + e0 + er) * L + l0 + lg];
            *(float4*)&Bs[er][lg] = x4;
        }
        __syncthreads();
        #pragma unroll
        for (int kk = 0; kk < 16; kk++) {
            float4 a4 = *(const float4*)&As[kk][ty * 4];
            float4 x4 = *(const float4*)&Bs[kk][tx * 4];
            float av[4] = {a4.x, a4.y, a4.z, a4.w};
            float xv[4] = {x4.x, x4.y, x4.z, x4.w};
            #pragma unroll
            for (int i = 0; i < 4; i++)
                #pragma unroll
                for (int j = 0; j < 4; j++) acc[i][j] += av[i] * xv[j];
        }
        __syncthreads();
    }
    float be0 = b_enc[a0 + ty * 4 + 0];
    float be1 = b_enc[a0 + ty * 4 + 1];
    float be2 = b_enc[a0 + ty * 4 + 2];
    float be3 = b_enc[a0 + ty * 4 + 3];
    #pragma unroll
    for (int j = 0; j < 4; j++) {
        int l = l0 + tx * 4 + j;
        float4 o = {acc[0][j] + be0, acc[1][j] + be1, acc[2][j] + be2, acc[3][j] + be3};
        *(float4*)&weT[((size_t)b * L + l) * ATTN + a0 + ty * 4] = o;
    }
}

// ---------------- fused out(ts-1)+attn(ts): 2 blocks per b (h = half), 512 threads ----------------
// c double-buffered. h0's logits/argmax/emb tail moved AFTER context (off pre-sync path).
// ts==0: skip out-part (wd=b_dec). ts==TMAX: out-part only (immediate logits).
__global__ __launch_bounds__(512) void k_aof(const float* __restrict__ gpart,
                                             const float* __restrict__ bgr,
                                             const float* __restrict__ WoutT,
                                             const float* __restrict__ b_out,
                                             const float* __restrict__ emb_table,
                                             const float* __restrict__ WdT,
                                             const float* __restrict__ b_dec,
                                             const float* __restrict__ c_in,
                                             float* __restrict__ c_out,
                                             float* __restrict__ logp_out,
                                             float* __restrict__ preds_out,
                                             float* __restrict__ Xcat,
                                             const float* __restrict__ weT,
                                             const float* __restrict__ v_e,
                                             const float* __restrict__ b_e,
                                             const float* __restrict__ enc_out,
                                             float* __restrict__ attn_out,
                                             float* __restrict__ scp,
                                             int* __restrict__ flags, int ts) {
    __shared__ float hs[DEC];
    __shared__ float wd_l[256];
    __shared__ float vel[256];
    __shared__ float al[L];
    __shared__ float red[512];
    __shared__ float rv[128];
    __shared__ int ri[128];
    __shared__ float redw[256][2];
    int b = blockIdx.x >> 1, h = blockIdx.x & 1;
    int t = threadIdx.x;
    int* flag = flags + b * 16;

    if (ts > 0) {
        // ===== out-part for step ts-1 (cell from c_in -> c_out, own-half writes) =====
        #pragma unroll
        for (int q = 0; q < 2; q++) {
            int d = q * 512 + t;
            const float* gp = gpart + (size_t)b * G4 + d * 4;
            float4 g = *(const float4*)gp;
            #pragma unroll
            for (int ks = 1; ks < 4; ks++) {
                float4 p = *(const float4*)(gp + (size_t)ks * BS * G4);
                g.x += p.x; g.y += p.y; g.z += p.z; g.w += p.w;
            }
            float4 bb = *(const float4*)&bgr[(size_t)d * 4];
            float gi = g.x + bb.x, gf = g.y + bb.y, gg = g.z + bb.z, go = g.w + bb.w;
            float fi = 1.f / (1.f + expf(-gi));
            float ff = 1.f / (1.f + expf(-gf));
            float fg = tanhf(gg);
            float fo = 1.f / (1.f + expf(-go));
            size_t ix = (size_t)b * DEC + d;
            float cn = ff * c_in[ix] + fi * fg;
            float hn = fo * tanhf(cn);
            if (q == h) {  // own half only: disjoint writes across the pair
                c_out[ix] = cn;
                Xcat[(size_t)b * KCAT + EMB + ENC + d] = hn;
            }
            hs[d] = hn;
        }
        __syncthreads();
        if (ts == TMAX) {  // epilogue: immediate full logits on h0, no attn follows
            if (h == 0) {
                int v = t & 127, kh = t >> 7;
                const float* wp = WoutT + (size_t)kh * 256 * VOCAB + v;
                float acc = 0.f;
                #pragma unroll 8
                for (int k = 0; k < 256; k++) acc += wp[(size_t)k * VOCAB] * hs[kh * 256 + k];
                red[t] = acc;
                __syncthreads();
                float logits = 0.f;
                if (t < 128) {
                    logits = ((red[t] + red[t + 128]) + (red[t + 256] + red[t + 384])) + b_out[t];
                    rv[t] = logits; ri[t] = t;
                }
                __syncthreads();
                for (int s = 64; s; s >>= 1) {
                    if (t < s) {
                        float ov = rv[t + s]; int oi = ri[t + s];
                        if (ov > rv[t] || (ov == rv[t] && oi < ri[t])) { rv[t] = ov; ri[t] = oi; }
                    }
                    __syncthreads();
                }
                float m = rv[0]; int am = ri[0];
                __syncthreads();
                if (t < 128) red[t] = expf(logits - m);
                __syncthreads();
                for (int s = 64; s; s >>= 1) { if (t < s && t + s < 128) red[t] += red[t + s]; __syncthreads(); }
                if (t < 128) logp_out[((size_t)b * TMAX + (ts - 1)) * VOCAB + t] = logits - m - logf(red[0]);
                if (t == 0) preds_out[(size_t)b * TMAX + (ts - 1)] = (float)am;
            }
            return;
        }
        // wdec own a-half into LDS: a = h*256 + (t>>1), 2-way k-split (R20-verbatim)
        {
            int a_l = t >> 1, ksub = t & 1;
            int a = h * 256 + a_l;
            const float* wdp = WdT + (size_t)(ksub * 512) * ATTN + a;
            float s = 0.f;
            #pragma unroll 16
            for (int k = 0; k < 512; k++) s += wdp[(size_t)k * ATTN] * hs[ksub * 512 + k];
            redw[a_l][ksub] = s;
        }
        __syncthreads();
        if (t < 256) {
            wd_l[t] = (redw[t][0] + redw[t][1]) + b_dec[h * 256 + t];
            vel[t] = v_e[h * 256 + t];
        }
    } else {
        if (t < 256) {
            wd_l[t] = b_dec[h * 256 + t];  // h0 = 0
            vel[t] = v_e[h * 256 + t];
        }
    }
    __syncthreads();

    // ===== score partials over own a-half, ALL 512 rows (R20-verbatim) =====
    {
        int ah = t & 1;
        #pragma unroll
        for (int rr = 0; rr < 2; rr++) {
            int l = rr * 256 + (t >> 1);
            const float* row = weT + ((size_t)b * L + l) * ATTN + h * 256 + ah * 128;
            float acc = 0.f;
            #pragma unroll 8
            for (int a4 = 0; a4 < 128; a4 += 4) {
                float4 x = *(const float4*)&row[a4];
                int a = ah * 128 + a4;
                acc += vel[a + 0] * tanh_fast(x.x + wd_l[a + 0]);
                acc += vel[a + 1] * tanh_fast(x.y + wd_l[a + 1]);
                acc += vel[a + 2] * tanh_fast(x.z + wd_l[a + 2]);
                acc += vel[a + 3] * tanh_fast(x.w + wd_l[a + 3]);
            }
            acc += __shfl_xor(acc, 1, 64);
            if (ah == 0) scp[((size_t)h * BS + b) * L + l] = acc;
        }
    }
    pairsync(flag, 2 * (ts + 1));  // ONE pairsync per step

    // ===== combine + softmax over 512 (R20-verbatim tree) =====
    float sc = scp[(size_t)b * L + t] + scp[((size_t)BS + b) * L + t] + b_e[0];
    red[t] = sc;
    __syncthreads();
    for (int s = 256; s; s >>= 1) { if (t < s) red[t] = fmaxf(red[t], red[t + s]); __syncthreads(); }
    float m = red[0];
    __syncthreads();
    float e = expf(sc - m);
    red[t] = e;
    __syncthreads();
    for (int s = 256; s; s >>= 1) { if (t < s) red[t] += red[t + s]; __syncthreads(); }
    float inv = 1.f / red[0];
    al[t] = e * inv;
    __syncthreads();
    if (h == 0) attn_out[((size_t)b * TMAX + ts) * L + t] = al[t];

    // ===== context for own e-half: 256 rows, 2 threads/row (R20-verbatim) =====
    {
        int r2 = t >> 1, lh2 = (t & 1) * 256;
        int e_ = h * 256 + r2;
        const float* erow = enc_out + ((size_t)b * ENC + e_) * L + lh2;
        float cacc = 0.f;
        #pragma unroll 8
        for (int l4 = 0; l4 < 256; l4 += 4) {
            float4 x = *(const float4*)&erow[l4];
            float4 a4 = *(const float4*)&al[lh2 + l4];
            cacc += x.x * a4.x + x.y * a4.y + x.z * a4.z + x.w * a4.w;
        }
        cacc += __shfl_xor(cacc, 1, 64);
        if ((t & 1) == 0) Xcat[(size_t)b * KCAT + EMB + e_] = cacc;
    }

    // ===== h0 tail: logits(ts-1) + argmax + logp + preds + emb (R22 body, relocated) =====
    if (h == 0 && ts > 0) {
        __syncthreads();  // red/rv/ri reuse; h,ts block-uniform -> legal
        int v = t & 127, kh = t >> 7;
        const float* wp = WoutT + (size_t)kh * 256 * VOCAB + v;
        float acc = 0.f;
        #pragma unroll 8
        for (int k = 0; k < 256; k++) acc += wp[(size_t)k * VOCAB] * hs[kh * 256 + k];
        red[t] = acc;
        __syncthreads();
        float logits = 0.f;
        if (t < 128) {
            logits = ((red[t] + red[t + 128]) + (red[t + 256] + red[t + 384])) + b_out[t];
            rv[t] = logits; ri[t] = t;
        }
        __syncthreads();
        for (int s = 64; s; s >>= 1) {
            if (t < s) {
                float ov = rv[t + s]; int oi = ri[t + s];
                if (ov > rv[t] || (ov == rv[t] && oi < ri[t])) { rv[t] = ov; ri[t] = oi; }
            }
            __syncthreads();
        }
        float m2 = rv[0]; int am = ri[0];
        __syncthreads();
        if (t < 128) red[t] = expf(logits - m2);
        __syncthreads();
        for (int s = 64; s; s >>= 1) { if (t < s && t + s < 128) red[t] += red[t + s]; __syncthreads(); }
        if (t < 128) logp_out[((size_t)b * TMAX + (ts - 1)) * VOCAB + t] = logits - m2 - logf(red[0]);
        if (t == 0) preds_out[(size_t)b * TMAX + (ts - 1)] = (float)am;
        if (t < 256) Xcat[(size_t)b * KCAT + t] = emb_table[(size_t)am * EMB + t];
    }
}

// ---------------- gates GEMM partials: K-split x4, b-split x2 (64-b tiles, R13-proven) ----------------
// grid (64, 2, 4): 64 m'-rows x 64 b x 448 K per block -> gpart[ks][b][m']
__global__ __launch_bounds__(256) void k_gates(const float* __restrict__ Wgr,
                                               const float* __restrict__ Xcat,
                                               float* __restrict__ gates_part) {
    __shared__ float As[16][68];
    __shared__ float Xs[16][68];
    int M0 = blockIdx.x * 64;
    int b0 = blockIdx.y * 64;
    int ks = blockIdx.z;
    int kbase = ks * 448, kend = kbase + 448;
    int t = threadIdx.x, ty = t >> 4, tx = t & 15;
    int r = t >> 2, kg = (t & 3) << 2;
    float acc[4][4] = {};
    float4 wreg = *(const float4*)&Wgr[(size_t)(M0 + r) * KCAT + kbase + kg];
    float4 xreg = *(const float4*)&Xcat[(size_t)(b0 + r) * KCAT + kbase + kg];
    for (int k0 = kbase; k0 < kend; k0 += 16) {
        As[kg + 0][r] = wreg.x; As[kg + 1][r] = wreg.y; As[kg + 2][r] = wreg.z; As[kg + 3][r] = wreg.w;
        Xs[kg + 0][r] = xreg.x; Xs[kg + 1][r] = xreg.y; Xs[kg + 2][r] = xreg.z; Xs[kg + 3][r] = xreg.w;
        __syncthreads();
        if (k0 + 16 < kend) {
            wreg = *(const float4*)&Wgr[(size_t)(M0 + r) * KCAT + k0 + 16 + kg];
            xreg = *(const float4*)&Xcat[(size_t)(b0 + r) * KCAT + k0 + 16 + kg];
        }
        #pragma unroll
        for (int kk = 0; kk < 16; kk++) {
            float4 a4 = *(const float4*)&As[kk][ty * 4];
            float4 x4 = *(const float4*)&Xs[kk][tx * 4];
            float av[4] = {a4.x, a4.y, a4.z, a4.w};
            float xv[4] = {x4.x, x4.y, x4.z, x4.w};
            #pragma unroll
            for (int i = 0; i < 4; i++)
                #pragma unroll
                for (int j = 0; j < 4; j++) acc[i][j] += av[i] * xv[j];
        }
        __syncthreads();
    }
    float* gp = gates_part + (size_t)ks * BS * G4;
    #pragma unroll
    for (int j = 0; j < 4; j++) {
        float4 o = {acc[0][j], acc[1][j], acc[2][j], acc[3][j]};
        *(float4*)&gp[(size_t)(b0 + tx * 4 + j) * G4 + M0 + ty * 4] = o;
    }
}

extern "C" void kernel_launch(void* const* d_in, const int* in_sizes, int n_in,
                              void* d_out, int out_size, void* d_ws, size_t ws_size,
                              hipStream_t stream) {
    const float* enc_out = (const float*)d_in[0];
    const float* W_enc   = (const float*)d_in[1];
    const float* b_enc   = (const float*)d_in[2];
    const float* W_dec   = (const float*)d_in[3];
    const float* b_dec   = (const float*)d_in[4];
    const float* v_e     = (const float*)d_in[5];
    const float* b_e     = (const float*)d_in[6];
    const float* emb     = (const float*)d_in[7];
    const float* W_ih    = (const float*)d_in[8];
    const float* W_hh    = (const float*)d_in[9];
    const float* b_ih    = (const float*)d_in[10];
    const float* b_hh    = (const float*)d_in[11];
    const float* W_out   = (const float*)d_in[12];
    const float* b_out   = (const float*)d_in[13];

    float* ws    = (float*)d_ws;
    float* weT   = ws + OFF_WET;
    float* Wgr   = ws + OFF_WGR;
    float* bgr   = ws + OFF_BGR;
    float* WoutT = ws + OFF_WOUTT;
    float* WdT   = ws + OFF_WDT;
    float* c0    = ws + OFF_C0;
    float* c1    = ws + OFF_C1;
    float* scp   = ws + OFF_SCP;
    float* Xcat  = ws + OFF_XCAT;
    float* gpart = ws + OFF_GPART;
    int*   flags = (int*)(ws + OFF_FLAG);

    float* logp_out  = (float*)d_out;
    float* preds_out = logp_out + (size_t)BS * TMAX * VOCAB;
    float* attn_out  = preds_out + (size_t)BS * TMAX;

    {
        long n = (long)G4 * KCAT + G4 + (long)DEC * VOCAB + (long)DEC * ATTN;
        k_prep<<<(int)((n + 255) / 256), 256, 0, stream>>>(W_ih, W_hh, b_ih, b_hh, W_out, W_dec,
                                                           Wgr, bgr, WoutT, WdT);
    }
    {
        long n = (long)BS * DEC + (long)BS * KCAT;
        k_init<<<(int)((n + 255) / 256), 256, 0, stream>>>(emb, c0, c1, Xcat, flags);
    }
    k_wenc<<<dim3(8, 8, 128), 256, 0, stream>>>(W_enc, b_enc, enc_out, weT);

    for (int t = 0; t < TMAX; t++) {
        float* cin  = (t & 1) ? c1 : c0;
        float* cout = (t & 1) ? c0 : c1;
        k_aof<<<256, 512, 0, stream>>>(gpart, bgr, WoutT, b_out, emb, WdT, b_dec,
                                       cin, cout, logp_out, preds_out, Xcat, weT,
                                       v_e, b_e, enc_out, attn_out, scp, flags, t);
        k_gates<<<dim3(64, 2, 4), 256, 0, stream>>>(Wgr, Xcat, gpart);
    }
    // epilogue: out-part for step TMAX-1 (c_in = c0 since TMAX is even)
    k_aof<<<256, 512, 0, stream>>>(gpart, bgr, WoutT, b_out, emb, WdT, b_dec,
                                   c0, c1, logp_out, preds_out, Xcat, weT,
                                   v_e, b_e, enc_out, attn_out, scp, flags, TMAX);
}